// Round 7
// baseline (9997.927 us; speedup 1.0000x reference)
//
#include <hip/hip_runtime.h>
#include <hip/hip_bf16.h>
#include <cstdio>

// SHRED: 2-layer LSTM (B=64,T=512,I=64,H=512) + MLP decoder 512->1024->2048->16384.
//
// Round 7: 4x arithmetic intensity -> 4x less MALL traffic.
//   R5/R6 post-mortem: identical perf with totally different register/LDS
//   signatures => not spill-bound. Dominant cost = per-step sc1 (MALL) h
//   re-read: 256 WGs x 64KB = 24MB/step + 256-WG barrier. B-fragments (h) are
//   utile-independent -> reuse each loaded fragment for 4 weight tiles.
// New shape: 64 WGs x 256 thr. WG w<32: layer0 utiles 4w..4w+3; w>=32: layer1.
//   Per wave: 4 utiles x NK MFMAs per step; h read ONCE per WG (not per utile).
//   MALL read traffic ~6MB/step; 64-WG barrier (flags), wave0 polls.
// Weights: plain cached global loads (WG-private 72-128KB pack -> L2-resident;
//   compiler pipelines 16B loads into MFMA stream). No LDS.
// Barrier protocol (fence-free, R4-proven): h stores sc1 -> vmcnt(0) ->
//   __syncthreads -> tid0 flag store (sc1) -> wave0 polls 64 flags -> sync.
// A-tile row order j_local = u_local*4 + gate => lane's 4 acc regs = i,f,g,o
// of one (unit,batch) pair -> pointwise update lane-local; cell state in regs.

#define B_  64
#define T_  512
#define I_  64
#define H_  512
#define D1_ 1024
#define D2_ 2048
#define O_  16384

typedef __attribute__((ext_vector_type(8))) short bf16x8_t;
typedef __attribute__((ext_vector_type(4))) float f32x4_t;
typedef unsigned short ushort_t;

__device__ inline ushort_t f2bf(float f) {
    return __builtin_bit_cast(ushort_t, __float2bfloat16(f));
}
__device__ inline float sigm(float x) { return 1.0f / (1.0f + __expf(-x)); }
__device__ inline float tanhf_(float x) {
    float cx = fminf(fmaxf(x, -15.f), 15.f);
    float e = __expf(2.f * cx);
    return (e - 1.f) / (e + 1.f);
}

// ---- prep kernels (run once per call, cheap) -------------------------------

// packL0: [128 utiles][18 ksteps][64 lanes][8] bf16.
// A-frag: lane l holds rows j_local=l&15, k = kk*32 + 8*(l>>4) + i.
// j_local = u_local*4 + gate; weight row = gate*H + u.
// K-concat for layer0: [h0_prev (512) ; x_t (64)] -> Whh0 then Wih0.
__global__ void pack_l0(const float* __restrict__ Wih0, const float* __restrict__ Whh0,
                        ushort_t* __restrict__ pack) {
    int idx = blockIdx.x * 256 + threadIdx.x;       // < 128*18*64
    int l  = idx & 63;
    int kk = (idx >> 6) % 18;
    int tu = idx / (18 * 64);
    int jl = l & 15, g8 = (l >> 4) * 8;
    int gate = jl & 3, u = tu * 4 + (jl >> 2);
    int wrow = gate * H_ + u;
    int kg = kk * 32 + g8;                          // chunk of 8 never straddles 512
    const float* s = (kg < H_) ? (Whh0 + (size_t)wrow * H_ + kg)
                               : (Wih0 + (size_t)wrow * I_ + (kg - H_));
    ushort_t* d = pack + (size_t)idx * 8;
#pragma unroll
    for (int i = 0; i < 8; i++) d[i] = f2bf(s[i]);
}

// packL1: [128][32][64][8]. K-concat: [h0_t (512); h1_prev (512)] -> Wih1 then Whh1.
__global__ void pack_l1(const float* __restrict__ Wih1, const float* __restrict__ Whh1,
                        ushort_t* __restrict__ pack) {
    int idx = blockIdx.x * 256 + threadIdx.x;       // < 128*32*64
    int l  = idx & 63;
    int kk = (idx >> 6) & 31;
    int tu = idx >> 11;
    int jl = l & 15, g8 = (l >> 4) * 8;
    int gate = jl & 3, u = tu * 4 + (jl >> 2);
    int wrow = gate * H_ + u;
    int kg = kk * 32 + g8;
    const float* s = (kg < H_) ? (Wih1 + (size_t)wrow * H_ + kg)
                               : (Whh1 + (size_t)wrow * H_ + (kg - H_));
    ushort_t* d = pack + (size_t)idx * 8;
#pragma unroll
    for (int i = 0; i < 8; i++) d[i] = f2bf(s[i]);
}

// bsum[layer][u][gate] = bih[gate*H+u] + bhh[gate*H+u]
__global__ void pack_bias(const float* __restrict__ bih0, const float* __restrict__ bhh0,
                          const float* __restrict__ bih1, const float* __restrict__ bhh1,
                          float* __restrict__ bsum) {
    int idx = blockIdx.x * 256 + threadIdx.x;       // < 4096
    int layer = idx >> 11;
    int rest = idx & 2047;
    int u = rest >> 2, gate = rest & 3;
    const float* a = layer ? bih1 : bih0;
    const float* b = layer ? bhh1 : bhh0;
    bsum[idx] = a[gate * H_ + u] + b[gate * H_ + u];
}

// x[B][T][I] fp32 -> xbf[T][B][I] bf16
__global__ void conv_x(const float* __restrict__ x, ushort_t* __restrict__ xbf) {
    int idx = blockIdx.x * 256 + threadIdx.x;       // < 64*512*64
    int c = idx & 63;
    int t = (idx >> 6) & 511;
    int b = idx >> 15;
    xbf[(size_t)t * 4096 + b * 64 + c] = f2bf(x[idx]);
}

// ---- persistent recurrent kernel -------------------------------------------

#define NWG 64

// Fence-free barrier. flags[w] = completed iters of WG w (monotone, sc1).
__device__ inline void grid_barrier(unsigned int* flags, int iter, int tid, int wg) {
    asm volatile("s_waitcnt vmcnt(0)" ::: "memory");    // own stores at MALL
    __syncthreads();                                     // whole WG done
    unsigned int target = (unsigned int)(iter + 1);
    if (tid == 0)
        __hip_atomic_store(&flags[wg], target, __ATOMIC_RELAXED,
                           __HIP_MEMORY_SCOPE_AGENT);
    if (tid < 64) {
        for (;;) {
            unsigned int f;
            asm volatile("global_load_dword %0, %1, off sc0 sc1"
                         : "=v"(f) : "v"(flags + tid));
            asm volatile("s_waitcnt vmcnt(0)" ::: "memory");
            if (__all(f >= target)) break;
            __builtin_amdgcn_s_sleep(2);
        }
    }
    __syncthreads();                                     // release all waves
}

template <int LAYER>
__device__ void run_layer(int wg, int tid,
                          const ushort_t* __restrict__ pack,
                          const float* __restrict__ bsum,
                          const ushort_t* __restrict__ xbf,
                          ushort_t* __restrict__ hbuf0,
                          ushort_t* __restrict__ hbuf1,
                          unsigned int* __restrict__ flags)
{
    constexpr int NK = LAYER ? 32 : 18;
    constexpr int UG = 4;                           // utiles per wave
    int l = tid & 63, v = tid >> 6;
    int u_loc = l >> 4;
    int bb = v * 16 + (l & 15);
    int g8 = u_loc * 8;
    int tu0 = (LAYER ? (wg - 32) : wg) * UG;

    // per-utile weight bases (lane-dependent, consecutive packs)
    const ushort_t* wbase[UG];
    float bi[UG][4];
    float creg[UG];
#pragma unroll
    for (int t = 0; t < UG; ++t) {
        wbase[t] = pack + (size_t)(tu0 + t) * (NK * 512) + l * 8;
        int u = (tu0 + t) * 4 + u_loc;
        const float* bp = bsum + LAYER * 2048 + u * 4;
        bi[t][0] = bp[0]; bi[t][1] = bp[1]; bi[t][2] = bp[2]; bi[t][3] = bp[3];
        creg[t] = 0.0f;
    }

    const int HS = 64 * 512;
    for (int k = 0; k <= T_; ++k) {
        bool active = LAYER ? (k >= 1) : (k < T_);
        if (active) {
            // both layers read h0[k-1] from slot (k+1)&1
            const ushort_t* h0r = hbuf0 + ((k + 1) & 1) * HS + bb * 512;
            // layer0 K-tail: x_t (read-only, plain cached);
            // layer1 K-tail: h1[k-2] slot k&1 (sc1)
            const ushort_t* srcHi = LAYER ? (hbuf1 + (k & 1) * HS + bb * 512)
                                          : (xbf + (size_t)k * 4096 + bb * 64);
            // h fragments ONCE per wave (sc1, pipelined), reused by 4 utiles
            bf16x8_t bfr[NK];
#pragma unroll
            for (int kk = 0; kk < NK; ++kk) {
                if (!LAYER && kk >= 16) {
                    bfr[kk] = *(const bf16x8_t*)(srcHi + (kk - 16) * 32 + g8);
                } else {
                    const ushort_t* q = (kk < 16) ? (h0r + kk * 32 + g8)
                                                  : (srcHi + (kk - 16) * 32 + g8);
                    asm volatile("global_load_dwordx4 %0, %1, off sc0 sc1"
                                 : "=v"(bfr[kk]) : "v"(q));
                }
            }
            asm volatile("s_waitcnt vmcnt(0)" ::: "memory");
            __builtin_amdgcn_sched_barrier(0);
            f32x4_t acc[UG];
#pragma unroll
            for (int t = 0; t < UG; ++t) {
                acc[t][0] = bi[t][0]; acc[t][1] = bi[t][1];
                acc[t][2] = bi[t][2]; acc[t][3] = bi[t][3];
            }
            // weights from cached global (L2-resident), compiler-pipelined
#pragma unroll
            for (int kk = 0; kk < NK; ++kk) {
#pragma unroll
                for (int t = 0; t < UG; ++t) {
                    bf16x8_t a = *(const bf16x8_t*)(wbase[t] + kk * 512);
                    acc[t] = __builtin_amdgcn_mfma_f32_16x16x32_bf16(a, bfr[kk], acc[t], 0, 0, 0);
                }
            }
            // pointwise + store per utile
            ushort_t* hw = LAYER ? (hbuf1 + ((k + 1) & 1) * HS)
                                 : (hbuf0 + (k & 1) * HS);
#pragma unroll
            for (int t = 0; t < UG; ++t) {
                float xi = sigm(acc[t][0]);
                float xf = sigm(acc[t][1]);
                float xg = tanhf_(acc[t][2]);
                float xo = sigm(acc[t][3]);
                creg[t] = xf * creg[t] + xi * xg;
                float hn = xo * tanhf_(creg[t]);
                unsigned int mine = (unsigned int)f2bf(hn);
                unsigned int other = (unsigned int)__shfl_xor((int)mine, 16, 64);
                if ((u_loc & 1) == 0) {
                    int u = (tu0 + t) * 4 + u_loc;
                    unsigned int valp = mine | (other << 16);
                    __hip_atomic_store((unsigned int*)(hw + (size_t)bb * 512 + u), valp,
                                       __ATOMIC_RELAXED, __HIP_MEMORY_SCOPE_AGENT);
                }
            }
        }
        if (k < T_)                                  // last iter: no one reads after
            grid_barrier(flags, k, tid, wg);
    }
}

__global__ __launch_bounds__(256, 1) void lstm_persist(
    const ushort_t* __restrict__ packL0, const ushort_t* __restrict__ packL1,
    const float* __restrict__ bsum, const ushort_t* __restrict__ xbf,
    ushort_t* __restrict__ hbuf0, ushort_t* __restrict__ hbuf1,
    unsigned int* __restrict__ flags)
{
    int w = blockIdx.x, tid = threadIdx.x;
    if (w < 32)
        run_layer<0>(w, tid, packL0, bsum, xbf, hbuf0, hbuf1, flags);
    else
        run_layer<1>(w, tid, packL1, bsum, xbf, hbuf0, hbuf1, flags);
}

// ---- decoder GEMM: out[64][ncols] = act[64][K] @ W[ncols][K]^T + bias ------
template <int NK, bool RELU, bool OUTBF>
__global__ __launch_bounds__(256) void dec_gemm(
    const float* __restrict__ W, const float* __restrict__ bias,
    const ushort_t* __restrict__ act, void* __restrict__ outp, int ncols)
{
    int tile = blockIdx.x, tid = threadIdx.x;
    int l = tid & 63, v = tid >> 6;
    int bb = v * 16 + (l & 15);
    int jA = tile * 16 + (l & 15);
    int g8 = (l >> 4) * 8;
    const float* wrow = W + (size_t)jA * (NK * 32);
    const ushort_t* arow = act + (size_t)bb * (NK * 32);
    f32x4_t acc = {0.f, 0.f, 0.f, 0.f};
    for (int kk = 0; kk < NK; ++kk) {
        int kg = kk * 32 + g8;
        float4 w0 = *(const float4*)(wrow + kg);
        float4 w1 = *(const float4*)(wrow + kg + 4);
        bf16x8_t af;
        af[0] = (short)f2bf(w0.x); af[1] = (short)f2bf(w0.y);
        af[2] = (short)f2bf(w0.z); af[3] = (short)f2bf(w0.w);
        af[4] = (short)f2bf(w1.x); af[5] = (short)f2bf(w1.y);
        af[6] = (short)f2bf(w1.z); af[7] = (short)f2bf(w1.w);
        bf16x8_t bf = *(const bf16x8_t*)(arow + kg);
        acc = __builtin_amdgcn_mfma_f32_16x16x32_bf16(af, bf, acc, 0, 0, 0);
    }
    int j0 = tile * 16 + (l >> 4) * 4;
    float r[4];
#pragma unroll
    for (int i = 0; i < 4; i++) {
        r[i] = acc[i] + bias[j0 + i];
        if (RELU) r[i] = fmaxf(r[i], 0.f);
    }
    if (OUTBF) {
        ushort_t* o = (ushort_t*)outp + (size_t)bb * ncols + j0;
        unsigned int lo = (unsigned)f2bf(r[0]) | ((unsigned)f2bf(r[1]) << 16);
        unsigned int hi = (unsigned)f2bf(r[2]) | ((unsigned)f2bf(r[3]) << 16);
        uint2 q; q.x = lo; q.y = hi;
        *(uint2*)o = q;
    } else {
        float* o = (float*)outp + (size_t)bb * ncols + j0;
        float4 t4; t4.x = r[0]; t4.y = r[1]; t4.z = r[2]; t4.w = r[3];
        *(float4*)o = t4;
    }
}

// ---- host ------------------------------------------------------------------
extern "C" void kernel_launch(void* const* d_in, const int* in_sizes, int n_in,
                              void* d_out, int out_size, void* d_ws, size_t ws_size,
                              hipStream_t stream)
{
    const float* x    = (const float*)d_in[0];
    const float* Wih0 = (const float*)d_in[1];
    const float* Whh0 = (const float*)d_in[2];
    const float* bih0 = (const float*)d_in[3];
    const float* bhh0 = (const float*)d_in[4];
    const float* Wih1 = (const float*)d_in[5];
    const float* Whh1 = (const float*)d_in[6];
    const float* bih1 = (const float*)d_in[7];
    const float* bhh1 = (const float*)d_in[8];
    const float* W1   = (const float*)d_in[9];
    const float* b1   = (const float*)d_in[10];
    const float* W2   = (const float*)d_in[11];
    const float* b2   = (const float*)d_in[12];
    const float* W3   = (const float*)d_in[13];
    const float* b3   = (const float*)d_in[14];

    char* ws = (char*)d_ws;
    size_t off = 0;
    auto take = [&](size_t bytes) -> char* {
        char* p = ws + off;
        off = (off + bytes + 255) & ~(size_t)255;
        return p;
    };
    ushort_t* packL0 = (ushort_t*)take((size_t)128 * 18 * 64 * 8 * 2);  // 2.25 MiB
    ushort_t* packL1 = (ushort_t*)take((size_t)128 * 32 * 64 * 8 * 2);  // 4 MiB
    float*    bsum   = (float*)take(2 * 2048 * 4);
    ushort_t* xbf    = (ushort_t*)take((size_t)512 * 64 * 64 * 2);      // 4 MiB
    char* zbase = ws + off;
    ushort_t* hbuf0  = (ushort_t*)take(2 * 64 * 512 * 2);
    ushort_t* hbuf1  = (ushort_t*)take(2 * 64 * 512 * 2);
    unsigned int* flags = (unsigned int*)take(NWG * 4);
    size_t zbytes = (size_t)((ws + off) - zbase);
    ushort_t* y1 = (ushort_t*)take(64 * 1024 * 2);
    ushort_t* y2 = (ushort_t*)take(64 * 2048 * 2);
    if (off > ws_size) {
        fprintf(stderr, "kernel_launch: ws too small: need %zu have %zu\n", off, ws_size);
        return;
    }

    // prep (every call; deterministic)
    pack_l0<<<(128 * 18 * 64) / 256, 256, 0, stream>>>(Wih0, Whh0, packL0);
    pack_l1<<<(128 * 32 * 64) / 256, 256, 0, stream>>>(Wih1, Whh1, packL1);
    pack_bias<<<16, 256, 0, stream>>>(bih0, bhh0, bih1, bhh1, bsum);
    conv_x<<<(64 * 512 * 64) / 256, 256, 0, stream>>>(x, xbf);
    hipMemsetAsync(zbase, 0, zbytes, stream);   // zero h rings + barrier flags

    // whole recurrence in one persistent kernel (513 internal iterations)
    lstm_persist<<<NWG, 256, 0, stream>>>(packL0, packL1, bsum, xbf,
                                          hbuf0, hbuf1, flags);

    // final top hidden state h1[511] lives in slot 1
    const ushort_t* h1f = hbuf1 + 1 * (64 * 512);
    dec_gemm<16, true,  true ><<<  64, 256, 0, stream>>>(W1, b1, h1f, y1, D1_);
    dec_gemm<32, true,  true ><<< 128, 256, 0, stream>>>(W2, b2, y1, y2, D2_);
    dec_gemm<64, false, false><<<1024, 256, 0, stream>>>(W3, b3, y2, d_out, O_);
}

// Round 8
// 4990.172 us; speedup vs baseline: 2.0035x; 2.0035x over previous
//
#include <hip/hip_runtime.h>
#include <hip/hip_bf16.h>
#include <cstdio>

// SHRED: 2-layer LSTM (B=64,T=512,I=64,H=512) + MLP decoder 512->1024->2048->16384.
//
// Round 8: halve MALL traffic, keep weights LDS-resident.
//   R7 post-mortem: per-step L2 weight re-reads (no residency) regressed 2x =>
//   weights MUST stay on-CU (LDS, R6-proven). R6's 10.65us/step ~= 4us latency
//   chain + 24.6MB/step / ~3.5TB/s MALL. Fix: 128 WGs x 2 utiles -> each WG
//   reads h ONCE, reuses for 2 weight tiles: 12.3 MB/step, 128-flag barrier.
// WG w<64: layer0 utiles {2w,2w+1} (36KB LDS used); w>=64: layer1 utiles
//   {2(w-64),...} (64KB LDS). Pipeline-skewed: iter k computes h0[k], h1[k-1].
// Barrier (fence-free, R4-proven): h stores sc1 -> vmcnt(0) -> __syncthreads ->
//   tid0 flag store sc1 -> wave0 polls 128 flags (uint2/lane) -> __syncthreads.
// A-tile row order j_local = u_local*4 + gate => lane's 4 acc regs = i,f,g,o
// of one (unit,batch) pair -> pointwise update lane-local; cell state in regs.

#define B_  64
#define T_  512
#define I_  64
#define H_  512
#define D1_ 1024
#define D2_ 2048
#define O_  16384

typedef __attribute__((ext_vector_type(8))) short bf16x8_t;
typedef __attribute__((ext_vector_type(4))) float f32x4_t;
typedef unsigned short ushort_t;

__device__ inline ushort_t f2bf(float f) {
    return __builtin_bit_cast(ushort_t, __float2bfloat16(f));
}
__device__ inline float sigm(float x) { return 1.0f / (1.0f + __expf(-x)); }
__device__ inline float tanhf_(float x) {
    float cx = fminf(fmaxf(x, -15.f), 15.f);
    float e = __expf(2.f * cx);
    return (e - 1.f) / (e + 1.f);
}

// ---- prep kernels (run once per call, cheap) -------------------------------

// packL0: [128 utiles][18 ksteps][64 lanes][8] bf16.
// A-frag: lane l holds rows j_local=l&15, k = kk*32 + 8*(l>>4) + i.
// j_local = u_local*4 + gate; weight row = gate*H + u.
// K-concat for layer0: [h0_prev (512) ; x_t (64)] -> Whh0 then Wih0.
__global__ void pack_l0(const float* __restrict__ Wih0, const float* __restrict__ Whh0,
                        ushort_t* __restrict__ pack) {
    int idx = blockIdx.x * 256 + threadIdx.x;       // < 128*18*64
    int l  = idx & 63;
    int kk = (idx >> 6) % 18;
    int tu = idx / (18 * 64);
    int jl = l & 15, g8 = (l >> 4) * 8;
    int gate = jl & 3, u = tu * 4 + (jl >> 2);
    int wrow = gate * H_ + u;
    int kg = kk * 32 + g8;                          // chunk of 8 never straddles 512
    const float* s = (kg < H_) ? (Whh0 + (size_t)wrow * H_ + kg)
                               : (Wih0 + (size_t)wrow * I_ + (kg - H_));
    ushort_t* d = pack + (size_t)idx * 8;
#pragma unroll
    for (int i = 0; i < 8; i++) d[i] = f2bf(s[i]);
}

// packL1: [128][32][64][8]. K-concat: [h0_t (512); h1_prev (512)] -> Wih1 then Whh1.
__global__ void pack_l1(const float* __restrict__ Wih1, const float* __restrict__ Whh1,
                        ushort_t* __restrict__ pack) {
    int idx = blockIdx.x * 256 + threadIdx.x;       // < 128*32*64
    int l  = idx & 63;
    int kk = (idx >> 6) & 31;
    int tu = idx >> 11;
    int jl = l & 15, g8 = (l >> 4) * 8;
    int gate = jl & 3, u = tu * 4 + (jl >> 2);
    int wrow = gate * H_ + u;
    int kg = kk * 32 + g8;
    const float* s = (kg < H_) ? (Wih1 + (size_t)wrow * H_ + kg)
                               : (Whh1 + (size_t)wrow * H_ + (kg - H_));
    ushort_t* d = pack + (size_t)idx * 8;
#pragma unroll
    for (int i = 0; i < 8; i++) d[i] = f2bf(s[i]);
}

// bsum[layer][u][gate] = bih[gate*H+u] + bhh[gate*H+u]
__global__ void pack_bias(const float* __restrict__ bih0, const float* __restrict__ bhh0,
                          const float* __restrict__ bih1, const float* __restrict__ bhh1,
                          float* __restrict__ bsum) {
    int idx = blockIdx.x * 256 + threadIdx.x;       // < 4096
    int layer = idx >> 11;
    int rest = idx & 2047;
    int u = rest >> 2, gate = rest & 3;
    const float* a = layer ? bih1 : bih0;
    const float* b = layer ? bhh1 : bhh0;
    bsum[idx] = a[gate * H_ + u] + b[gate * H_ + u];
}

// x[B][T][I] fp32 -> xbf[T][B][I] bf16
__global__ void conv_x(const float* __restrict__ x, ushort_t* __restrict__ xbf) {
    int idx = blockIdx.x * 256 + threadIdx.x;       // < 64*512*64
    int c = idx & 63;
    int t = (idx >> 6) & 511;
    int b = idx >> 15;
    xbf[(size_t)t * 4096 + b * 64 + c] = f2bf(x[idx]);
}

// ---- persistent recurrent kernel -------------------------------------------

#define NWG 128

// Fence-free barrier. flags[w] = completed iters of WG w (monotone, sc1).
__device__ inline void grid_barrier(unsigned int* flags, int iter, int tid, int wg) {
    asm volatile("s_waitcnt vmcnt(0)" ::: "memory");    // own stores at MALL
    __syncthreads();                                     // whole WG done
    unsigned int target = (unsigned int)(iter + 1);
    if (tid == 0)
        __hip_atomic_store(&flags[wg], target, __ATOMIC_RELAXED,
                           __HIP_MEMORY_SCOPE_AGENT);
    if (tid < 64) {
        const uint2* fp = (const uint2*)flags;           // 128 flags = 64 x uint2
        for (;;) {
            uint2 f;
            asm volatile("global_load_dwordx2 %0, %1, off sc0 sc1"
                         : "=v"(f) : "v"(fp + tid));
            asm volatile("s_waitcnt vmcnt(0)" ::: "memory");
            if (__all((f.x >= target) & (f.y >= target))) break;
            __builtin_amdgcn_s_sleep(1);
        }
    }
    __syncthreads();                                     // release all waves
}

template <int LAYER>
__device__ void run_layer(int wg, int tid,
                          const ushort_t* __restrict__ pack,
                          const float* __restrict__ bsum,
                          const ushort_t* __restrict__ xbf,
                          ushort_t* __restrict__ hbuf0,
                          ushort_t* __restrict__ hbuf1,
                          unsigned int* __restrict__ flags,
                          uint4* aLDS)
{
    constexpr int NK = LAYER ? 32 : 18;
    constexpr int UG = 2;                           // utiles per wave
    int l = tid & 63, v = tid >> 6;
    int u_loc = l >> 4;
    int bb = v * 16 + (l & 15);
    int g8 = u_loc * 8;
    int tu0 = (LAYER ? (wg - 64) : wg) * UG;

    // Stage BOTH utile packs into LDS once (contiguous: utiles tu0, tu0+1).
    {
        const uint4* s4 = (const uint4*)(pack + (size_t)tu0 * (NK * 512));
        for (int i = tid; i < UG * NK * 64; i += 256) aLDS[i] = s4[i];
    }
    __syncthreads();
    const bf16x8_t* aFr = (const bf16x8_t*)aLDS;    // [t*NK + kk][lane]

    float bi[UG][4];
    float creg[UG];
#pragma unroll
    for (int t = 0; t < UG; ++t) {
        int u = (tu0 + t) * 4 + u_loc;
        const float* bp = bsum + LAYER * 2048 + u * 4;
        bi[t][0] = bp[0]; bi[t][1] = bp[1]; bi[t][2] = bp[2]; bi[t][3] = bp[3];
        creg[t] = 0.0f;
    }

    const int HS = 64 * 512;
    for (int k = 0; k <= T_; ++k) {
        bool active = LAYER ? (k >= 1) : (k < T_);
        if (active) {
            // both layers read h0[k-1] from slot (k+1)&1
            const ushort_t* h0r = hbuf0 + ((k + 1) & 1) * HS + bb * 512;
            // layer0 K-tail: x_t (read-only, plain cached);
            // layer1 K-tail: h1[k-2] slot k&1 (sc1)
            const ushort_t* srcHi = LAYER ? (hbuf1 + (k & 1) * HS + bb * 512)
                                          : (xbf + (size_t)k * 4096 + bb * 64);
            // h fragments ONCE per wave (sc1, pipelined), reused by UG utiles
            bf16x8_t bfr[NK];
#pragma unroll
            for (int kk = 0; kk < NK; ++kk) {
                if (!LAYER && kk >= 16) {
                    bfr[kk] = *(const bf16x8_t*)(srcHi + (kk - 16) * 32 + g8);
                } else {
                    const ushort_t* q = (kk < 16) ? (h0r + kk * 32 + g8)
                                                  : (srcHi + (kk - 16) * 32 + g8);
                    asm volatile("global_load_dwordx4 %0, %1, off sc0 sc1"
                                 : "=v"(bfr[kk]) : "v"(q));
                }
            }
            asm volatile("s_waitcnt vmcnt(0)" ::: "memory");
            __builtin_amdgcn_sched_barrier(0);
            f32x4_t acc[UG];
#pragma unroll
            for (int t = 0; t < UG; ++t) {
                acc[t][0] = bi[t][0]; acc[t][1] = bi[t][1];
                acc[t][2] = bi[t][2]; acc[t][3] = bi[t][3];
            }
            // A from LDS (ds_read_b128, compiler-scheduled lgkmcnt), 2 acc chains
#pragma unroll
            for (int kk = 0; kk < NK; ++kk) {
#pragma unroll
                for (int t = 0; t < UG; ++t) {
                    bf16x8_t a = aFr[(t * NK + kk) * 64 + l];
                    acc[t] = __builtin_amdgcn_mfma_f32_16x16x32_bf16(a, bfr[kk], acc[t], 0, 0, 0);
                }
            }
            // pointwise + store per utile
            ushort_t* hw = LAYER ? (hbuf1 + ((k + 1) & 1) * HS)
                                 : (hbuf0 + (k & 1) * HS);
#pragma unroll
            for (int t = 0; t < UG; ++t) {
                float xi = sigm(acc[t][0]);
                float xf = sigm(acc[t][1]);
                float xg = tanhf_(acc[t][2]);
                float xo = sigm(acc[t][3]);
                creg[t] = xf * creg[t] + xi * xg;
                float hn = xo * tanhf_(creg[t]);
                unsigned int mine = (unsigned int)f2bf(hn);
                unsigned int other = (unsigned int)__shfl_xor((int)mine, 16, 64);
                if ((u_loc & 1) == 0) {
                    int u = (tu0 + t) * 4 + u_loc;
                    unsigned int valp = mine | (other << 16);
                    __hip_atomic_store((unsigned int*)(hw + (size_t)bb * 512 + u), valp,
                                       __ATOMIC_RELAXED, __HIP_MEMORY_SCOPE_AGENT);
                }
            }
        }
        if (k < T_)                                  // last iter: no one reads after
            grid_barrier(flags, k, tid, wg);
    }
}

__global__ __launch_bounds__(256, 1) void lstm_persist(
    const ushort_t* __restrict__ packL0, const ushort_t* __restrict__ packL1,
    const float* __restrict__ bsum, const ushort_t* __restrict__ xbf,
    ushort_t* __restrict__ hbuf0, ushort_t* __restrict__ hbuf1,
    unsigned int* __restrict__ flags)
{
    __shared__ uint4 aLDS[4096];                    // 64 KiB (L1 uses all, L0 36KB)
    int w = blockIdx.x, tid = threadIdx.x;
    if (w < 64)
        run_layer<0>(w, tid, packL0, bsum, xbf, hbuf0, hbuf1, flags, aLDS);
    else
        run_layer<1>(w, tid, packL1, bsum, xbf, hbuf0, hbuf1, flags, aLDS);
}

// ---- decoder GEMM: out[64][ncols] = act[64][K] @ W[ncols][K]^T + bias ------
template <int NK, bool RELU, bool OUTBF>
__global__ __launch_bounds__(256) void dec_gemm(
    const float* __restrict__ W, const float* __restrict__ bias,
    const ushort_t* __restrict__ act, void* __restrict__ outp, int ncols)
{
    int tile = blockIdx.x, tid = threadIdx.x;
    int l = tid & 63, v = tid >> 6;
    int bb = v * 16 + (l & 15);
    int jA = tile * 16 + (l & 15);
    int g8 = (l >> 4) * 8;
    const float* wrow = W + (size_t)jA * (NK * 32);
    const ushort_t* arow = act + (size_t)bb * (NK * 32);
    f32x4_t acc = {0.f, 0.f, 0.f, 0.f};
    for (int kk = 0; kk < NK; ++kk) {
        int kg = kk * 32 + g8;
        float4 w0 = *(const float4*)(wrow + kg);
        float4 w1 = *(const float4*)(wrow + kg + 4);
        bf16x8_t af;
        af[0] = (short)f2bf(w0.x); af[1] = (short)f2bf(w0.y);
        af[2] = (short)f2bf(w0.z); af[3] = (short)f2bf(w0.w);
        af[4] = (short)f2bf(w1.x); af[5] = (short)f2bf(w1.y);
        af[6] = (short)f2bf(w1.z); af[7] = (short)f2bf(w1.w);
        bf16x8_t bf = *(const bf16x8_t*)(arow + kg);
        acc = __builtin_amdgcn_mfma_f32_16x16x32_bf16(af, bf, acc, 0, 0, 0);
    }
    int j0 = tile * 16 + (l >> 4) * 4;
    float r[4];
#pragma unroll
    for (int i = 0; i < 4; i++) {
        r[i] = acc[i] + bias[j0 + i];
        if (RELU) r[i] = fmaxf(r[i], 0.f);
    }
    if (OUTBF) {
        ushort_t* o = (ushort_t*)outp + (size_t)bb * ncols + j0;
        unsigned int lo = (unsigned)f2bf(r[0]) | ((unsigned)f2bf(r[1]) << 16);
        unsigned int hi = (unsigned)f2bf(r[2]) | ((unsigned)f2bf(r[3]) << 16);
        uint2 q; q.x = lo; q.y = hi;
        *(uint2*)o = q;
    } else {
        float* o = (float*)outp + (size_t)bb * ncols + j0;
        float4 t4; t4.x = r[0]; t4.y = r[1]; t4.z = r[2]; t4.w = r[3];
        *(float4*)o = t4;
    }
}

// ---- host ------------------------------------------------------------------
extern "C" void kernel_launch(void* const* d_in, const int* in_sizes, int n_in,
                              void* d_out, int out_size, void* d_ws, size_t ws_size,
                              hipStream_t stream)
{
    const float* x    = (const float*)d_in[0];
    const float* Wih0 = (const float*)d_in[1];
    const float* Whh0 = (const float*)d_in[2];
    const float* bih0 = (const float*)d_in[3];
    const float* bhh0 = (const float*)d_in[4];
    const float* Wih1 = (const float*)d_in[5];
    const float* Whh1 = (const float*)d_in[6];
    const float* bih1 = (const float*)d_in[7];
    const float* bhh1 = (const float*)d_in[8];
    const float* W1   = (const float*)d_in[9];
    const float* b1   = (const float*)d_in[10];
    const float* W2   = (const float*)d_in[11];
    const float* b2   = (const float*)d_in[12];
    const float* W3   = (const float*)d_in[13];
    const float* b3   = (const float*)d_in[14];

    char* ws = (char*)d_ws;
    size_t off = 0;
    auto take = [&](size_t bytes) -> char* {
        char* p = ws + off;
        off = (off + bytes + 255) & ~(size_t)255;
        return p;
    };
    ushort_t* packL0 = (ushort_t*)take((size_t)128 * 18 * 64 * 8 * 2);  // 2.25 MiB
    ushort_t* packL1 = (ushort_t*)take((size_t)128 * 32 * 64 * 8 * 2);  // 4 MiB
    float*    bsum   = (float*)take(2 * 2048 * 4);
    ushort_t* xbf    = (ushort_t*)take((size_t)512 * 64 * 64 * 2);      // 4 MiB
    char* zbase = ws + off;
    ushort_t* hbuf0  = (ushort_t*)take(2 * 64 * 512 * 2);
    ushort_t* hbuf1  = (ushort_t*)take(2 * 64 * 512 * 2);
    unsigned int* flags = (unsigned int*)take(NWG * 4);
    size_t zbytes = (size_t)((ws + off) - zbase);
    ushort_t* y1 = (ushort_t*)take(64 * 1024 * 2);
    ushort_t* y2 = (ushort_t*)take(64 * 2048 * 2);
    if (off > ws_size) {
        fprintf(stderr, "kernel_launch: ws too small: need %zu have %zu\n", off, ws_size);
        return;
    }

    // prep (every call; deterministic)
    pack_l0<<<(128 * 18 * 64) / 256, 256, 0, stream>>>(Wih0, Whh0, packL0);
    pack_l1<<<(128 * 32 * 64) / 256, 256, 0, stream>>>(Wih1, Whh1, packL1);
    pack_bias<<<16, 256, 0, stream>>>(bih0, bhh0, bih1, bhh1, bsum);
    conv_x<<<(64 * 512 * 64) / 256, 256, 0, stream>>>(x, xbf);
    hipMemsetAsync(zbase, 0, zbytes, stream);   // zero h rings + barrier flags

    // whole recurrence in one persistent kernel (513 internal iterations)
    lstm_persist<<<NWG, 256, 0, stream>>>(packL0, packL1, bsum, xbf,
                                          hbuf0, hbuf1, flags);

    // final top hidden state h1[511] lives in slot 1
    const ushort_t* h1f = hbuf1 + 1 * (64 * 512);
    dec_gemm<16, true,  true ><<<  64, 256, 0, stream>>>(W1, b1, h1f, y1, D1_);
    dec_gemm<32, true,  true ><<< 128, 256, 0, stream>>>(W2, b2, y1, y2, D2_);
    dec_gemm<64, false, false><<<1024, 256, 0, stream>>>(W3, b3, y2, d_out, O_);
}